// Round 9
// baseline (116.887 us; speedup 1.0000x reference)
//
#include <hip/hip_runtime.h>

#define DEV __device__ __forceinline__
typedef short s16x8 __attribute__((ext_vector_type(8)));
typedef float f32x16 __attribute__((ext_vector_type(16)));
typedef unsigned short u16;

#define WAIT_VMCNT(N) asm volatile("s_waitcnt vmcnt(" #N ")" ::: "memory")
#define CFENCE asm volatile("" ::: "memory")

DEV unsigned cvt_pk_bf16(float lo, float hi) {
  unsigned r;
  asm volatile("v_cvt_pk_bf16_f32 %0, %1, %2" : "=v"(r) : "v"(lo), "v"(hi));
  return r;
}
DEV u16 f2bf(float f) {
  unsigned u = __builtin_bit_cast(unsigned, f);
  unsigned r = u + 0x7fffu + ((u >> 16) & 1u);
  return (u16)(r >> 16);
}
DEV float bf2f(u16 u) { return __builtin_bit_cast(float, (unsigned)u << 16); }
DEV f32x16 zero16() {
  f32x16 v;
  #pragma unroll
  for (int i = 0; i < 16; ++i) v[i] = 0.f;
  return v;
}

// async global->LDS: 16B per lane, LDS dest = wave-uniform base + lane*16
DEV void gld16(const u16* g, u16* l) {
  __builtin_amdgcn_global_load_lds(
      (const __attribute__((address_space(1))) void*)g,
      (__attribute__((address_space(3))) void*)l, 16, 0, 0);
}

// stage 64x64 bf16 tile (row stride `stride`) into frag-swizzled LDS (2 issues/thread)
DEV void stage_tile64(const u16* __restrict__ gbase, size_t stride, u16* lbuf, int t) {
  #pragma unroll
  for (int p = 0; p < 2; ++p) {
    int c = p * 256 + t;
    int row = c >> 3, s = c & 7;
    int gck = s ^ (row & 7);
    const u16* src = gbase + (size_t)row * stride + gck * 8;
    u16* dst = lbuf + (size_t)(p * 256 + (t & 192)) * 8;  // wave-uniform base
    gld16(src, dst);
  }
}

DEV s16x8 frag(const u16* buf, int row, int chunk) {
  return *(const s16x8*)(buf + row * 64 + ((chunk ^ (row & 7)) << 3));
}

DEV int kswz(int row, int d) {  // scalar-element address in frag-swizzled 64x64 tile
  return row * 64 + ((((d >> 3) ^ (row & 7)) << 3) | (d & 7));
}

DEV void stage_wt(const float* __restrict__ src, u16* dst, int t) {
  // src: [64 f][64 g] f32 row-major -> dst[g][f] bf16, frag-swizzled
  #pragma unroll
  for (int r = 0; r < 4; ++r) {
    int e = (r * 256 + t) * 4;
    int f = e >> 6, g0 = e & 63;
    float4 v = *(const float4*)(src + f * 64 + g0);
    float vv[4] = {v.x, v.y, v.z, v.w};
    #pragma unroll
    for (int j = 0; j < 4; ++j) {
      int g = g0 + j;
      dst[g * 64 + ((((f >> 3) ^ (g & 7)) << 3) | (f & 7))] = f2bf(vv[j]);
    }
  }
}

// ---------------- kernel 1: projections (grid (32 batch, 16 tile)) ----------------
// Kbf = bf16(X@attW); Vt = bf16(X@W) transposed [b][d][n]; Bb = bf16(X@selfW+bias);
// scal_ws = a.sum(0) (block (0,0) only)
__global__ __launch_bounds__(256) void prep_kernel(
    const float* __restrict__ X, const float* __restrict__ W,
    const float* __restrict__ attW, const float* __restrict__ Aa,
    const float* __restrict__ biasW, const float* __restrict__ selfW,
    u16* __restrict__ Kbf, u16* __restrict__ Vt, u16* __restrict__ Bb,
    float* __restrict__ scal_ws) {
  __shared__ __align__(16) u16 Xl[64 * 64];  // reused for K output
  __shared__ __align__(16) u16 Wt[3][64 * 64];
  __shared__ __align__(16) u16 Bl[64 * 64];
  __shared__ __align__(16) u16 Vl[64 * 72];  // 144B row stride
  __shared__ float sc4[4][64];

  const int t = threadIdx.x;
  const int b = blockIdx.x;
  const int n0 = blockIdx.y * 64;
  const int r0 = b * 1024 + n0;
  const bool sblk = (blockIdx.x == 0 && blockIdx.y == 0);
  const int lane = t & 63, w = t >> 6, h = lane >> 5, ln = lane & 31;
  const int rg = (w >> 1) * 32;  // row group
  const int cf = w & 1;          // col half
  const int d = cf * 32 + ln;

  if (sblk) {  // scale = a.sum(axis=0)
    int qt = t >> 6, dd = t & 63;
    float s = 0.f;
    #pragma unroll
    for (int i = 0; i < 16; ++i) s += Aa[(qt * 16 + i) * 64 + dd];
    sc4[qt][dd] = s;
  }

  // stage X tile 64x64 f32 -> bf16 frag-swizzled
  #pragma unroll
  for (int p = 0; p < 2; ++p) {
    int c = p * 256 + t;
    int row = c >> 3, ck = c & 7;
    const float4* src = (const float4*)(X + (size_t)(r0 + row) * 64 + ck * 8);
    float4 a0 = src[0], a1 = src[1];
    unsigned* dst = (unsigned*)&Xl[row * 64 + ((ck ^ (row & 7)) << 3)];
    dst[0] = cvt_pk_bf16(a0.x, a0.y);
    dst[1] = cvt_pk_bf16(a0.z, a0.w);
    dst[2] = cvt_pk_bf16(a1.x, a1.y);
    dst[3] = cvt_pk_bf16(a1.z, a1.w);
  }
  stage_wt(attW, &Wt[0][0], t);
  stage_wt(W, &Wt[1][0], t);
  stage_wt(selfW, &Wt[2][0], t);
  __syncthreads();

  s16x8 xa[4];
  #pragma unroll
  for (int ks = 0; ks < 4; ++ks) xa[ks] = frag(Xl, rg + ln, ks * 2 + h);

  f32x16 aA = zero16(), aW = zero16(), aS = zero16();
  #pragma unroll
  for (int ks = 0; ks < 4; ++ks) {
    s16x8 bA = frag(&Wt[0][0], d, ks * 2 + h);
    s16x8 bW = frag(&Wt[1][0], d, ks * 2 + h);
    s16x8 bS = frag(&Wt[2][0], d, ks * 2 + h);
    aA = __builtin_amdgcn_mfma_f32_32x32x16_bf16(xa[ks], bA, aA, 0, 0, 0);
    aW = __builtin_amdgcn_mfma_f32_32x32x16_bf16(xa[ks], bW, aW, 0, 0, 0);
    aS = __builtin_amdgcn_mfma_f32_32x32x16_bf16(xa[ks], bS, aS, 0, 0, 0);
  }
  __syncthreads();  // all waves done reading Xl before K overwrites it

  const float bi = biasW[d];
  #pragma unroll
  for (int reg = 0; reg < 16; ++reg) {
    int rl = (reg & 3) + 8 * (reg >> 2) + 4 * h;
    int row = rg + rl;
    Xl[kswz(row, d)] = f2bf(aA[reg]);       // K tile
    Bl[kswz(row, d)] = f2bf(aS[reg] + bi);  // base tile
  }
  #pragma unroll
  for (int pg = 0; pg < 4; ++pg) {
    int n = rg + pg * 8 + 4 * h;
    *(unsigned*)&Vl[d * 72 + n] = cvt_pk_bf16(aW[pg * 4 + 0], aW[pg * 4 + 1]);
    *(unsigned*)&Vl[d * 72 + n + 2] = cvt_pk_bf16(aW[pg * 4 + 2], aW[pg * 4 + 3]);
  }
  __syncthreads();

  // vectorized global writes
  #pragma unroll
  for (int p = 0; p < 2; ++p) {
    int c = p * 256 + t;
    int row = c >> 3, ck = c & 7;
    size_t go = (size_t)(r0 + row) * 64 + ck * 8;
    int lo = row * 64 + ((ck ^ (row & 7)) << 3);
    *(s16x8*)&Kbf[go] = *(const s16x8*)&Xl[lo];
    *(s16x8*)&Bb[go] = *(const s16x8*)&Bl[lo];
  }
  #pragma unroll
  for (int p = 0; p < 2; ++p) {
    int c = p * 256 + t;
    int dd = c >> 3, ck = c & 7;
    *(s16x8*)&Vt[(size_t)(b * 64 + dd) * 1024 + n0 + ck * 8] =
        *(const s16x8*)&Vl[dd * 72 + ck * 8];
  }
  if (sblk && t < 64)
    scal_ws[t] = sc4[0][t] + sc4[1][t] + sc4[2][t] + sc4[3][t];
}

// P-processing: leaky + optional diag-zero + pack to P^T B-frag words
#define PROC(SV, DG, PWV)                                                      \
  do {                                                                         \
    float p_[16];                                                              \
    _Pragma("unroll") for (int r_ = 0; r_ < 16; ++r_) {                        \
      float v_ = (SV)[r_];                                                     \
      p_[r_] = fmaxf(v_, 0.f) + 0.01f * fminf(v_, 0.f);                        \
    }                                                                          \
    if (DG) {                                                                  \
      _Pragma("unroll") for (int r_ = 0; r_ < 16; ++r_) {                      \
        int rl_ = (r_ & 3) + 8 * (r_ >> 2) + 4 * h;                            \
        p_[r_] = (rl_ == ln) ? 0.f : p_[r_];                                   \
      }                                                                        \
    }                                                                          \
    unsigned pk_[8];                                                           \
    _Pragma("unroll") for (int i_ = 0; i_ < 8; ++i_)                           \
        pk_[i_] = cvt_pk_bf16(p_[2 * i_], p_[2 * i_ + 1]);                     \
    auto a0_ = __builtin_amdgcn_permlane32_swap(pk_[0], pk_[2], false, false); \
    auto a1_ = __builtin_amdgcn_permlane32_swap(pk_[1], pk_[3], false, false); \
    auto a2_ = __builtin_amdgcn_permlane32_swap(pk_[4], pk_[6], false, false); \
    auto a3_ = __builtin_amdgcn_permlane32_swap(pk_[5], pk_[7], false, false); \
    PWV[0][0] = a0_[0]; PWV[0][1] = a1_[0]; PWV[0][2] = a0_[1];                \
    PWV[0][3] = a1_[1]; PWV[1][0] = a2_[0]; PWV[1][1] = a3_[0];                \
    PWV[1][2] = a2_[1]; PWV[1][3] = a3_[1];                                    \
  } while (0)

// ---------------- kernel 2: fused leaky(mask(Q K^T)) @ V + base ----------------
// grid (32 batch, 8 q-tile of 128). Wave = 32 q-rows x full kv64:
// 16 MFMA per wave per staged tile, no cross-wave O reduction.
__global__ __launch_bounds__(256) void attn_kernel(
    const u16* __restrict__ Kbf, const u16* __restrict__ Vt,
    const u16* __restrict__ Bb, const float* __restrict__ scal_ws,
    float* __restrict__ Hout) {
  __shared__ __align__(16) u16 ring[3][2][4096];  // 48 KB ring-3 (K,V per slot)

  const int t = threadIdx.x;
  const int b = blockIdx.x;
  const int q0 = blockIdx.y * 128;
  const int lane = t & 63, w = t >> 6, h = lane >> 5, ln = lane & 31;
  const int qb = q0 + w * 32;  // wave's q rows: qb + ln

  const u16* Kg = Kbf + (size_t)b * 65536;
  const u16* Vg = Vt + (size_t)b * 65536;

  // prologue: stage tiles 0,1 (8 issues/thread)
  stage_tile64(Kg, 64, &ring[0][0][0], t);
  stage_tile64(Vg, 1024, &ring[0][1][0], t);
  stage_tile64(Kg + (size_t)64 * 64, 64, &ring[1][0][0], t);
  stage_tile64(Vg + 64, 1024, &ring[1][1][0], t);

  // Q^T B-frags = K rows (qb+ln) scaled per-feature by scal_ws
  s16x8 qf[4];
  #pragma unroll
  for (int ks = 0; ks < 4; ++ks) {
    s16x8 raw = *(const s16x8*)(Kg + (size_t)(qb + ln) * 64 + ks * 16 + h * 8);
    float4 sA = *(const float4*)(scal_ws + ks * 16 + h * 8);
    float4 sB = *(const float4*)(scal_ws + ks * 16 + h * 8 + 4);
    union { unsigned u[4]; s16x8 v; } qq;
    qq.u[0] = cvt_pk_bf16(bf2f((u16)raw[0]) * sA.x, bf2f((u16)raw[1]) * sA.y);
    qq.u[1] = cvt_pk_bf16(bf2f((u16)raw[2]) * sA.z, bf2f((u16)raw[3]) * sA.w);
    qq.u[2] = cvt_pk_bf16(bf2f((u16)raw[4]) * sB.x, bf2f((u16)raw[5]) * sB.y);
    qq.u[3] = cvt_pk_bf16(bf2f((u16)raw[6]) * sB.z, bf2f((u16)raw[7]) * sB.w);
    qf[ks] = qq.v;
  }

  f32x16 o0 = zero16(), o1 = zero16();  // O^T[d-half][q32] accumulators

  #pragma unroll 1
  for (int tix = 0; tix < 16; ++tix) {
    const int kv0 = tix * 64;
    if (tix < 15) {
      WAIT_VMCNT(4);  // tile tix staged; tile tix+1 in flight
    } else {
      WAIT_VMCNT(0);
    }
    __builtin_amdgcn_s_barrier();
    CFENCE;
    if (tix < 14) {  // stage tile tix+2 post-barrier into freed slot
      const int ns = (tix + 2) % 3;
      stage_tile64(Kg + (size_t)(kv0 + 128) * 64, 64, &ring[ns][0][0], t);
      stage_tile64(Vg + (kv0 + 128), 1024, &ring[ns][1][0], t);
    }
    const u16* Kl = &ring[tix % 3][0][0];
    const u16* Vl = &ring[tix % 3][1][0];

    // S^T[kv64][q32]: two kv-row-group chains, 8 MFMAs over K=64
    f32x16 s0 = zero16(), s1 = zero16();
    __builtin_amdgcn_s_setprio(1);
    #pragma unroll
    for (int ks = 0; ks < 4; ++ks) {
      s0 = __builtin_amdgcn_mfma_f32_32x32x16_bf16(frag(Kl, ln, ks * 2 + h), qf[ks], s0, 0, 0, 0);
      s1 = __builtin_amdgcn_mfma_f32_32x32x16_bf16(frag(Kl, 32 + ln, ks * 2 + h), qf[ks], s1, 0, 0, 0);
    }
    __builtin_amdgcn_s_setprio(0);

    const bool dg0 = (kv0 == qb);
    const bool dg1 = (kv0 + 32 == qb);
    unsigned pw0[2][4], pw1[2][4];
    PROC(s0, dg0, pw0);
    PROC(s1, dg1, pw1);

    // O^T += V^T * P^T : kv as K-dim (4 chunks of 16), 8 MFMAs
    __builtin_amdgcn_s_setprio(1);
    #pragma unroll
    for (int c = 0; c < 4; ++c) {
      union { unsigned u[4]; s16x8 v; } pb;
      pb.u[0] = (c < 2 ? pw0 : pw1)[c & 1][0];
      pb.u[1] = (c < 2 ? pw0 : pw1)[c & 1][1];
      pb.u[2] = (c < 2 ? pw0 : pw1)[c & 1][2];
      pb.u[3] = (c < 2 ? pw0 : pw1)[c & 1][3];
      o0 = __builtin_amdgcn_mfma_f32_32x32x16_bf16(frag(Vl, ln, c * 2 + h), pb.v, o0, 0, 0, 0);
      o1 = __builtin_amdgcn_mfma_f32_32x32x16_bf16(frag(Vl, 32 + ln, c * 2 + h), pb.v, o1, 0, 0, 0);
    }
    __builtin_amdgcn_s_setprio(0);
  }

  __syncthreads();  // ring readers done before epilogue reuses LDS

  // wave-local epilogue: O^T regs -> 8KB LDS region [q32][d64] -> coalesced out
  float* Ow = (float*)&ring[0][0][0] + (size_t)w * 2048;
  #pragma unroll
  for (int reg = 0; reg < 16; ++reg) {
    int rl = (reg & 3) + 8 * (reg >> 2) + 4 * h;
    int d0 = rl, d1 = 32 + rl;
    Ow[ln * 64 + ((((d0 >> 2) ^ (ln & 15)) << 2) | (d0 & 3))] = o0[reg];
    Ow[ln * 64 + ((((d1 >> 2) ^ (ln & 15)) << 2) | (d1 & 3))] = o1[reg];
  }
  // wave reads back only its own region (intra-wave LDS ordering suffices)
  #pragma unroll
  for (int p = 0; p < 8; ++p) {
    int row = p * 4 + (lane >> 4);  // 0..31
    int g = lane & 15;
    int off = row * 64 + ((g ^ (row & 15)) << 2);
    float4 v = *(const float4*)&Ow[off];
    size_t go = ((size_t)b * 1024 + qb + row) * 64 + g * 4;
    const short4 bv = *(const short4*)(Bb + go);
    v.x += bf2f((u16)bv.x);
    v.y += bf2f((u16)bv.y);
    v.z += bf2f((u16)bv.z);
    v.w += bf2f((u16)bv.w);
    *(float4*)(Hout + go) = v;
  }
}

extern "C" void kernel_launch(void* const* d_in, const int* in_sizes, int n_in,
                              void* d_out, int out_size, void* d_ws, size_t ws_size,
                              hipStream_t stream) {
  const float* X = (const float*)d_in[0];
  // d_in[1] = A : unused by the forward pass
  const float* W = (const float*)d_in[2];
  const float* attW = (const float*)d_in[3];
  const float* a = (const float*)d_in[4];
  const float* biasW = (const float*)d_in[5];
  const float* selfW = (const float*)d_in[6];
  float* H = (float*)d_out;

  u16* Kbf = (u16*)d_ws;                                // 4 MB
  u16* Vt = Kbf + (size_t)32 * 1024 * 64;               // 4 MB
  u16* Bb = Vt + (size_t)32 * 1024 * 64;                // 4 MB
  float* scal = (float*)(Bb + (size_t)32 * 1024 * 64);  // 256 B

  prep_kernel<<<dim3(32, 16), 256, 0, stream>>>(X, W, attW, a, biasW, selfW,
                                                Kbf, Vt, Bb, scal);
  // MEASUREMENT ROUND: attn x5 (idempotent — overwrites H with identical values).
  // Baseline R7: total = c + p + a = 34.4 us. This round: T = c + p + 5*(a+gap).
  // => attn+gap = (T - 34.4) / 4.
  for (int rep = 0; rep < 5; ++rep)
    attn_kernel<<<dim3(32, 8), 256, 0, stream>>>(Kbf, Vt, Bb, scal, H);
}

// Round 10
// 34.331 us; speedup vs baseline: 3.4047x; 3.4047x over previous
//
#include <hip/hip_runtime.h>

#define DEV __device__ __forceinline__
typedef short s16x8 __attribute__((ext_vector_type(8)));
typedef float f32x16 __attribute__((ext_vector_type(16)));
typedef unsigned short u16;

#define WAIT_VMCNT(N) asm volatile("s_waitcnt vmcnt(" #N ")" ::: "memory")
#define CFENCE asm volatile("" ::: "memory")

DEV unsigned cvt_pk_bf16(float lo, float hi) {
  unsigned r;
  asm volatile("v_cvt_pk_bf16_f32 %0, %1, %2" : "=v"(r) : "v"(lo), "v"(hi));
  return r;
}
DEV u16 f2bf(float f) {
  unsigned u = __builtin_bit_cast(unsigned, f);
  unsigned r = u + 0x7fffu + ((u >> 16) & 1u);
  return (u16)(r >> 16);
}
DEV float bf2f(u16 u) { return __builtin_bit_cast(float, (unsigned)u << 16); }
DEV f32x16 zero16() {
  f32x16 v;
  #pragma unroll
  for (int i = 0; i < 16; ++i) v[i] = 0.f;
  return v;
}

// async global->LDS: 16B per lane, LDS dest = wave-uniform base + lane*16
DEV void gld16(const u16* g, u16* l) {
  __builtin_amdgcn_global_load_lds(
      (const __attribute__((address_space(1))) void*)g,
      (__attribute__((address_space(3))) void*)l, 16, 0, 0);
}

// stage 64x64 bf16 tile (row stride `stride`) into frag-swizzled LDS (2 issues/thread)
DEV void stage_tile64(const u16* __restrict__ gbase, size_t stride, u16* lbuf, int t) {
  #pragma unroll
  for (int p = 0; p < 2; ++p) {
    int c = p * 256 + t;
    int row = c >> 3, s = c & 7;
    int gck = s ^ (row & 7);
    const u16* src = gbase + (size_t)row * stride + gck * 8;
    u16* dst = lbuf + (size_t)(p * 256 + (t & 192)) * 8;  // wave-uniform base
    gld16(src, dst);
  }
}

DEV s16x8 frag(const u16* buf, int row, int chunk) {
  return *(const s16x8*)(buf + row * 64 + ((chunk ^ (row & 7)) << 3));
}

DEV int kswz(int row, int d) {  // scalar-element address in frag-swizzled 64x64 tile
  return row * 64 + ((((d >> 3) ^ (row & 7)) << 3) | (d & 7));
}

DEV void stage_wt(const float* __restrict__ src, u16* dst, int t) {
  // src: [64 f][64 g] f32 row-major -> dst[g][f] bf16, frag-swizzled
  #pragma unroll
  for (int r = 0; r < 4; ++r) {
    int e = (r * 256 + t) * 4;
    int f = e >> 6, g0 = e & 63;
    float4 v = *(const float4*)(src + f * 64 + g0);
    float vv[4] = {v.x, v.y, v.z, v.w};
    #pragma unroll
    for (int j = 0; j < 4; ++j) {
      int g = g0 + j;
      dst[g * 64 + ((((f >> 3) ^ (g & 7)) << 3) | (f & 7))] = f2bf(vv[j]);
    }
  }
}

// ---------------- kernel 1: projections (grid (32 batch, 16 tile)) ----------------
// Kbf = bf16(X@attW); Vt = bf16(X@W) transposed [b][d][n]; Bb = bf16(X@selfW+bias);
// scal_ws = a.sum(0) (block (0,0) only)
__global__ __launch_bounds__(256) void prep_kernel(
    const float* __restrict__ X, const float* __restrict__ W,
    const float* __restrict__ attW, const float* __restrict__ Aa,
    const float* __restrict__ biasW, const float* __restrict__ selfW,
    u16* __restrict__ Kbf, u16* __restrict__ Vt, u16* __restrict__ Bb,
    float* __restrict__ scal_ws) {
  __shared__ __align__(16) u16 Xl[64 * 64];  // reused for K output
  __shared__ __align__(16) u16 Wt[3][64 * 64];
  __shared__ __align__(16) u16 Bl[64 * 64];
  __shared__ __align__(16) u16 Vl[64 * 72];  // 144B row stride
  __shared__ float sc4[4][64];

  const int t = threadIdx.x;
  const int b = blockIdx.x;
  const int n0 = blockIdx.y * 64;
  const int r0 = b * 1024 + n0;
  const bool sblk = (blockIdx.x == 0 && blockIdx.y == 0);
  const int lane = t & 63, w = t >> 6, h = lane >> 5, ln = lane & 31;
  const int rg = (w >> 1) * 32;  // row group
  const int cf = w & 1;          // col half
  const int d = cf * 32 + ln;

  if (sblk) {  // scale = a.sum(axis=0)
    int qt = t >> 6, dd = t & 63;
    float s = 0.f;
    #pragma unroll
    for (int i = 0; i < 16; ++i) s += Aa[(qt * 16 + i) * 64 + dd];
    sc4[qt][dd] = s;
  }

  // stage X tile 64x64 f32 -> bf16 frag-swizzled
  #pragma unroll
  for (int p = 0; p < 2; ++p) {
    int c = p * 256 + t;
    int row = c >> 3, ck = c & 7;
    const float4* src = (const float4*)(X + (size_t)(r0 + row) * 64 + ck * 8);
    float4 a0 = src[0], a1 = src[1];
    unsigned* dst = (unsigned*)&Xl[row * 64 + ((ck ^ (row & 7)) << 3)];
    dst[0] = cvt_pk_bf16(a0.x, a0.y);
    dst[1] = cvt_pk_bf16(a0.z, a0.w);
    dst[2] = cvt_pk_bf16(a1.x, a1.y);
    dst[3] = cvt_pk_bf16(a1.z, a1.w);
  }
  stage_wt(attW, &Wt[0][0], t);
  stage_wt(W, &Wt[1][0], t);
  stage_wt(selfW, &Wt[2][0], t);
  __syncthreads();

  s16x8 xa[4];
  #pragma unroll
  for (int ks = 0; ks < 4; ++ks) xa[ks] = frag(Xl, rg + ln, ks * 2 + h);

  f32x16 aA = zero16(), aW = zero16(), aS = zero16();
  #pragma unroll
  for (int ks = 0; ks < 4; ++ks) {
    s16x8 bA = frag(&Wt[0][0], d, ks * 2 + h);
    s16x8 bW = frag(&Wt[1][0], d, ks * 2 + h);
    s16x8 bS = frag(&Wt[2][0], d, ks * 2 + h);
    aA = __builtin_amdgcn_mfma_f32_32x32x16_bf16(xa[ks], bA, aA, 0, 0, 0);
    aW = __builtin_amdgcn_mfma_f32_32x32x16_bf16(xa[ks], bW, aW, 0, 0, 0);
    aS = __builtin_amdgcn_mfma_f32_32x32x16_bf16(xa[ks], bS, aS, 0, 0, 0);
  }
  __syncthreads();  // all waves done reading Xl before K overwrites it

  const float bi = biasW[d];
  #pragma unroll
  for (int reg = 0; reg < 16; ++reg) {
    int rl = (reg & 3) + 8 * (reg >> 2) + 4 * h;
    int row = rg + rl;
    Xl[kswz(row, d)] = f2bf(aA[reg]);       // K tile
    Bl[kswz(row, d)] = f2bf(aS[reg] + bi);  // base tile
  }
  #pragma unroll
  for (int pg = 0; pg < 4; ++pg) {
    int n = rg + pg * 8 + 4 * h;
    *(unsigned*)&Vl[d * 72 + n] = cvt_pk_bf16(aW[pg * 4 + 0], aW[pg * 4 + 1]);
    *(unsigned*)&Vl[d * 72 + n + 2] = cvt_pk_bf16(aW[pg * 4 + 2], aW[pg * 4 + 3]);
  }
  __syncthreads();

  // vectorized global writes
  #pragma unroll
  for (int p = 0; p < 2; ++p) {
    int c = p * 256 + t;
    int row = c >> 3, ck = c & 7;
    size_t go = (size_t)(r0 + row) * 64 + ck * 8;
    int lo = row * 64 + ((ck ^ (row & 7)) << 3);
    *(s16x8*)&Kbf[go] = *(const s16x8*)&Xl[lo];
    *(s16x8*)&Bb[go] = *(const s16x8*)&Bl[lo];
  }
  #pragma unroll
  for (int p = 0; p < 2; ++p) {
    int c = p * 256 + t;
    int dd = c >> 3, ck = c & 7;
    *(s16x8*)&Vt[(size_t)(b * 64 + dd) * 1024 + n0 + ck * 8] =
        *(const s16x8*)&Vl[dd * 72 + ck * 8];
  }
  if (sblk && t < 64)
    scal_ws[t] = sc4[0][t] + sc4[1][t] + sc4[2][t] + sc4[3][t];
}

// P-processing: leaky + optional diag-zero + pack to P^T B-frag words
#define PROC(SV, DG, PWV)                                                      \
  do {                                                                         \
    float p_[16];                                                              \
    _Pragma("unroll") for (int r_ = 0; r_ < 16; ++r_) {                        \
      float v_ = (SV)[r_];                                                     \
      p_[r_] = fmaxf(v_, 0.f) + 0.01f * fminf(v_, 0.f);                        \
    }                                                                          \
    if (DG) {                                                                  \
      _Pragma("unroll") for (int r_ = 0; r_ < 16; ++r_) {                      \
        int rl_ = (r_ & 3) + 8 * (r_ >> 2) + 4 * h;                            \
        p_[r_] = (rl_ == ln) ? 0.f : p_[r_];                                   \
      }                                                                        \
    }                                                                          \
    unsigned pk_[8];                                                           \
    _Pragma("unroll") for (int i_ = 0; i_ < 8; ++i_)                           \
        pk_[i_] = cvt_pk_bf16(p_[2 * i_], p_[2 * i_ + 1]);                     \
    auto a0_ = __builtin_amdgcn_permlane32_swap(pk_[0], pk_[2], false, false); \
    auto a1_ = __builtin_amdgcn_permlane32_swap(pk_[1], pk_[3], false, false); \
    auto a2_ = __builtin_amdgcn_permlane32_swap(pk_[4], pk_[6], false, false); \
    auto a3_ = __builtin_amdgcn_permlane32_swap(pk_[5], pk_[7], false, false); \
    PWV[0][0] = a0_[0]; PWV[0][1] = a1_[0]; PWV[0][2] = a0_[1];                \
    PWV[0][3] = a1_[1]; PWV[1][0] = a2_[0]; PWV[1][1] = a3_[0];                \
    PWV[1][2] = a2_[1]; PWV[1][3] = a3_[1];                                    \
  } while (0)

// ---------------- kernel 2: fused leaky(mask(Q K^T)) @ V + base ----------------
// grid (32 batch, 8 q-tile of 128). Wave = 32 q-rows x full kv64.
// Ring-4 / depth-3 prefetch + staggered kv start to desync the L2 burst.
__global__ __launch_bounds__(256) void attn_kernel(
    const u16* __restrict__ Kbf, const u16* __restrict__ Vt,
    const u16* __restrict__ Bb, const float* __restrict__ scal_ws,
    float* __restrict__ Hout) {
  __shared__ __align__(16) u16 ring[4][2][4096];  // 64 KB ring-4 (K,V per slot)

  const int t = threadIdx.x;
  const int b = blockIdx.x;
  const int qt = blockIdx.y;
  const int q0 = qt * 128;
  const int lane = t & 63, w = t >> 6, h = lane >> 5, ln = lane & 31;
  const int qb = q0 + w * 32;  // wave's q rows: qb + ln
  const int start = ((qt << 1) + (b >> 3)) & 15;  // staggered kv sweep start

  const u16* Kg = Kbf + (size_t)b * 65536;
  const u16* Vg = Vt + (size_t)b * 65536;

  // prologue: stage tiles seq 0,1,2 (12 issues/thread)
  #pragma unroll
  for (int i = 0; i < 3; ++i) {
    int tt = (start + i) & 15;
    stage_tile64(Kg + (size_t)tt * 64 * 64, 64, &ring[i][0][0], t);
    stage_tile64(Vg + tt * 64, 1024, &ring[i][1][0], t);
  }

  // Q^T B-frags = K rows (qb+ln) scaled per-feature by scal_ws
  s16x8 qf[4];
  #pragma unroll
  for (int ks = 0; ks < 4; ++ks) {
    s16x8 raw = *(const s16x8*)(Kg + (size_t)(qb + ln) * 64 + ks * 16 + h * 8);
    float4 sA = *(const float4*)(scal_ws + ks * 16 + h * 8);
    float4 sB = *(const float4*)(scal_ws + ks * 16 + h * 8 + 4);
    union { unsigned u[4]; s16x8 v; } qq;
    qq.u[0] = cvt_pk_bf16(bf2f((u16)raw[0]) * sA.x, bf2f((u16)raw[1]) * sA.y);
    qq.u[1] = cvt_pk_bf16(bf2f((u16)raw[2]) * sA.z, bf2f((u16)raw[3]) * sA.w);
    qq.u[2] = cvt_pk_bf16(bf2f((u16)raw[4]) * sB.x, bf2f((u16)raw[5]) * sB.y);
    qq.u[3] = cvt_pk_bf16(bf2f((u16)raw[6]) * sB.z, bf2f((u16)raw[7]) * sB.w);
    qf[ks] = qq.v;
  }

  f32x16 o0 = zero16(), o1 = zero16();  // O^T[d-half][q32] accumulators

  #pragma unroll 1
  for (int i = 0; i < 16; ++i) {
    const int tt = (start + i) & 15;
    const int kv0 = tt * 64;
    // depth-3: at iter i, seq i must be done; seq i+1, i+2 stay in flight (8)
    if (i <= 13) {
      WAIT_VMCNT(8);
    } else if (i == 14) {
      WAIT_VMCNT(4);
    } else {
      WAIT_VMCNT(0);
    }
    __builtin_amdgcn_s_barrier();
    CFENCE;
    if (i < 13) {  // stage seq i+3 post-barrier into freed slot
      const int nt_ = (start + i + 3) & 15;
      const int ns = (i + 3) & 3;
      stage_tile64(Kg + (size_t)nt_ * 64 * 64, 64, &ring[ns][0][0], t);
      stage_tile64(Vg + nt_ * 64, 1024, &ring[ns][1][0], t);
    }
    const u16* Kl = &ring[i & 3][0][0];
    const u16* Vl = &ring[i & 3][1][0];

    // S^T[kv64][q32]: two kv-row-group chains, 8 MFMAs over K=64
    f32x16 s0 = zero16(), s1 = zero16();
    __builtin_amdgcn_s_setprio(1);
    #pragma unroll
    for (int ks = 0; ks < 4; ++ks) {
      s0 = __builtin_amdgcn_mfma_f32_32x32x16_bf16(frag(Kl, ln, ks * 2 + h), qf[ks], s0, 0, 0, 0);
      s1 = __builtin_amdgcn_mfma_f32_32x32x16_bf16(frag(Kl, 32 + ln, ks * 2 + h), qf[ks], s1, 0, 0, 0);
    }
    __builtin_amdgcn_s_setprio(0);

    const bool dg0 = (kv0 == qb);
    const bool dg1 = (kv0 + 32 == qb);
    unsigned pw0[2][4], pw1[2][4];
    PROC(s0, dg0, pw0);
    PROC(s1, dg1, pw1);

    // O^T += V^T * P^T : kv as K-dim (4 chunks of 16), 8 MFMAs
    __builtin_amdgcn_s_setprio(1);
    #pragma unroll
    for (int c = 0; c < 4; ++c) {
      union { unsigned u[4]; s16x8 v; } pb;
      pb.u[0] = (c < 2 ? pw0 : pw1)[c & 1][0];
      pb.u[1] = (c < 2 ? pw0 : pw1)[c & 1][1];
      pb.u[2] = (c < 2 ? pw0 : pw1)[c & 1][2];
      pb.u[3] = (c < 2 ? pw0 : pw1)[c & 1][3];
      o0 = __builtin_amdgcn_mfma_f32_32x32x16_bf16(frag(Vl, ln, c * 2 + h), pb.v, o0, 0, 0, 0);
      o1 = __builtin_amdgcn_mfma_f32_32x32x16_bf16(frag(Vl, 32 + ln, c * 2 + h), pb.v, o1, 0, 0, 0);
    }
    __builtin_amdgcn_s_setprio(0);
  }

  __syncthreads();  // ring readers done before epilogue reuses LDS

  // wave-local epilogue: O^T regs -> 8KB LDS region [q32][d64] -> coalesced out
  float* Ow = (float*)&ring[0][0][0] + (size_t)w * 2048;
  #pragma unroll
  for (int reg = 0; reg < 16; ++reg) {
    int rl = (reg & 3) + 8 * (reg >> 2) + 4 * h;
    int d0 = rl, d1 = 32 + rl;
    Ow[ln * 64 + ((((d0 >> 2) ^ (ln & 15)) << 2) | (d0 & 3))] = o0[reg];
    Ow[ln * 64 + ((((d1 >> 2) ^ (ln & 15)) << 2) | (d1 & 3))] = o1[reg];
  }
  // wave reads back only its own region (intra-wave LDS ordering suffices)
  #pragma unroll
  for (int p = 0; p < 8; ++p) {
    int row = p * 4 + (lane >> 4);  // 0..31
    int g = lane & 15;
    int off = row * 64 + ((g ^ (row & 15)) << 2);
    float4 v = *(const float4*)&Ow[off];
    size_t go = ((size_t)b * 1024 + qb + row) * 64 + g * 4;
    const short4 bv = *(const short4*)(Bb + go);
    v.x += bf2f((u16)bv.x);
    v.y += bf2f((u16)bv.y);
    v.z += bf2f((u16)bv.z);
    v.w += bf2f((u16)bv.w);
    *(float4*)(Hout + go) = v;
  }
}

extern "C" void kernel_launch(void* const* d_in, const int* in_sizes, int n_in,
                              void* d_out, int out_size, void* d_ws, size_t ws_size,
                              hipStream_t stream) {
  const float* X = (const float*)d_in[0];
  // d_in[1] = A : unused by the forward pass
  const float* W = (const float*)d_in[2];
  const float* attW = (const float*)d_in[3];
  const float* a = (const float*)d_in[4];
  const float* biasW = (const float*)d_in[5];
  const float* selfW = (const float*)d_in[6];
  float* H = (float*)d_out;

  u16* Kbf = (u16*)d_ws;                                // 4 MB
  u16* Vt = Kbf + (size_t)32 * 1024 * 64;               // 4 MB
  u16* Bb = Vt + (size_t)32 * 1024 * 64;                // 4 MB
  float* scal = (float*)(Bb + (size_t)32 * 1024 * 64);  // 256 B

  prep_kernel<<<dim3(32, 16), 256, 0, stream>>>(X, W, attW, a, biasW, selfW,
                                                Kbf, Vt, Bb, scal);
  attn_kernel<<<dim3(32, 8), 256, 0, stream>>>(Kbf, Vt, Bb, scal, H);
}

// Round 11
// 33.955 us; speedup vs baseline: 3.4424x; 1.0111x over previous
//
#include <hip/hip_runtime.h>

#define DEV __device__ __forceinline__
typedef short s16x8 __attribute__((ext_vector_type(8)));
typedef float f32x16 __attribute__((ext_vector_type(16)));
typedef unsigned short u16;

#define WAIT_VMCNT(N) asm volatile("s_waitcnt vmcnt(" #N ")" ::: "memory")
#define CFENCE asm volatile("" ::: "memory")

DEV unsigned cvt_pk_bf16(float lo, float hi) {
  unsigned r;
  asm volatile("v_cvt_pk_bf16_f32 %0, %1, %2" : "=v"(r) : "v"(lo), "v"(hi));
  return r;
}
DEV u16 f2bf(float f) {
  unsigned u = __builtin_bit_cast(unsigned, f);
  unsigned r = u + 0x7fffu + ((u >> 16) & 1u);
  return (u16)(r >> 16);
}
DEV float bf2f(u16 u) { return __builtin_bit_cast(float, (unsigned)u << 16); }
DEV f32x16 zero16() {
  f32x16 v;
  #pragma unroll
  for (int i = 0; i < 16; ++i) v[i] = 0.f;
  return v;
}

// async global->LDS: 16B per lane, LDS dest = wave-uniform base + lane*16
DEV void gld16(const u16* g, u16* l) {
  __builtin_amdgcn_global_load_lds(
      (const __attribute__((address_space(1))) void*)g,
      (__attribute__((address_space(3))) void*)l, 16, 0, 0);
}

// stage 64x64 bf16 tile (row stride `stride`) into frag-swizzled LDS (2 issues/thread)
DEV void stage_tile64(const u16* __restrict__ gbase, size_t stride, u16* lbuf, int t) {
  #pragma unroll
  for (int p = 0; p < 2; ++p) {
    int c = p * 256 + t;
    int row = c >> 3, s = c & 7;
    int gck = s ^ (row & 7);
    const u16* src = gbase + (size_t)row * stride + gck * 8;
    u16* dst = lbuf + (size_t)(p * 256 + (t & 192)) * 8;  // wave-uniform base
    gld16(src, dst);
  }
}

DEV s16x8 frag(const u16* buf, int row, int chunk) {
  return *(const s16x8*)(buf + row * 64 + ((chunk ^ (row & 7)) << 3));
}

DEV int kswz(int row, int d) {  // scalar-element address in frag-swizzled 64x64 tile
  return row * 64 + ((((d >> 3) ^ (row & 7)) << 3) | (d & 7));
}

DEV void stage_wt(const float* __restrict__ src, u16* dst, int t) {
  // src: [64 f][64 g] f32 row-major -> dst[g][f] bf16, frag-swizzled
  #pragma unroll
  for (int r = 0; r < 4; ++r) {
    int e = (r * 256 + t) * 4;
    int f = e >> 6, g0 = e & 63;
    float4 v = *(const float4*)(src + f * 64 + g0);
    float vv[4] = {v.x, v.y, v.z, v.w};
    #pragma unroll
    for (int j = 0; j < 4; ++j) {
      int g = g0 + j;
      dst[g * 64 + ((((f >> 3) ^ (g & 7)) << 3) | (f & 7))] = f2bf(vv[j]);
    }
  }
}

// ---------------- kernel 1: projections (grid (32 batch, 16 tile)) ----------------
__global__ __launch_bounds__(256) void prep_kernel(
    const float* __restrict__ X, const float* __restrict__ W,
    const float* __restrict__ attW, const float* __restrict__ Aa,
    const float* __restrict__ biasW, const float* __restrict__ selfW,
    u16* __restrict__ Kbf, u16* __restrict__ Vt, u16* __restrict__ Bb,
    float* __restrict__ scal_ws) {
  __shared__ __align__(16) u16 Xl[64 * 64];  // reused for K output
  __shared__ __align__(16) u16 Wt[3][64 * 64];
  __shared__ __align__(16) u16 Bl[64 * 64];
  __shared__ __align__(16) u16 Vl[64 * 72];  // 144B row stride
  __shared__ float sc4[4][64];

  const int t = threadIdx.x;
  const int b = blockIdx.x;
  const int n0 = blockIdx.y * 64;
  const int r0 = b * 1024 + n0;
  const bool sblk = (blockIdx.x == 0 && blockIdx.y == 0);
  const int lane = t & 63, w = t >> 6, h = lane >> 5, ln = lane & 31;
  const int rg = (w >> 1) * 32;  // row group
  const int cf = w & 1;          // col half
  const int d = cf * 32 + ln;

  if (sblk) {  // scale = a.sum(axis=0)
    int qt = t >> 6, dd = t & 63;
    float s = 0.f;
    #pragma unroll
    for (int i = 0; i < 16; ++i) s += Aa[(qt * 16 + i) * 64 + dd];
    sc4[qt][dd] = s;
  }

  // stage X tile 64x64 f32 -> bf16 frag-swizzled
  #pragma unroll
  for (int p = 0; p < 2; ++p) {
    int c = p * 256 + t;
    int row = c >> 3, ck = c & 7;
    const float4* src = (const float4*)(X + (size_t)(r0 + row) * 64 + ck * 8);
    float4 a0 = src[0], a1 = src[1];
    unsigned* dst = (unsigned*)&Xl[row * 64 + ((ck ^ (row & 7)) << 3)];
    dst[0] = cvt_pk_bf16(a0.x, a0.y);
    dst[1] = cvt_pk_bf16(a0.z, a0.w);
    dst[2] = cvt_pk_bf16(a1.x, a1.y);
    dst[3] = cvt_pk_bf16(a1.z, a1.w);
  }
  stage_wt(attW, &Wt[0][0], t);
  stage_wt(W, &Wt[1][0], t);
  stage_wt(selfW, &Wt[2][0], t);
  __syncthreads();

  s16x8 xa[4];
  #pragma unroll
  for (int ks = 0; ks < 4; ++ks) xa[ks] = frag(Xl, rg + ln, ks * 2 + h);

  f32x16 aA = zero16(), aW = zero16(), aS = zero16();
  #pragma unroll
  for (int ks = 0; ks < 4; ++ks) {
    s16x8 bA = frag(&Wt[0][0], d, ks * 2 + h);
    s16x8 bW = frag(&Wt[1][0], d, ks * 2 + h);
    s16x8 bS = frag(&Wt[2][0], d, ks * 2 + h);
    aA = __builtin_amdgcn_mfma_f32_32x32x16_bf16(xa[ks], bA, aA, 0, 0, 0);
    aW = __builtin_amdgcn_mfma_f32_32x32x16_bf16(xa[ks], bW, aW, 0, 0, 0);
    aS = __builtin_amdgcn_mfma_f32_32x32x16_bf16(xa[ks], bS, aS, 0, 0, 0);
  }
  __syncthreads();  // all waves done reading Xl before K overwrites it

  const float bi = biasW[d];
  #pragma unroll
  for (int reg = 0; reg < 16; ++reg) {
    int rl = (reg & 3) + 8 * (reg >> 2) + 4 * h;
    int row = rg + rl;
    Xl[kswz(row, d)] = f2bf(aA[reg]);       // K tile
    Bl[kswz(row, d)] = f2bf(aS[reg] + bi);  // base tile
  }
  #pragma unroll
  for (int pg = 0; pg < 4; ++pg) {
    int n = rg + pg * 8 + 4 * h;
    *(unsigned*)&Vl[d * 72 + n] = cvt_pk_bf16(aW[pg * 4 + 0], aW[pg * 4 + 1]);
    *(unsigned*)&Vl[d * 72 + n + 2] = cvt_pk_bf16(aW[pg * 4 + 2], aW[pg * 4 + 3]);
  }
  __syncthreads();

  // vectorized global writes
  #pragma unroll
  for (int p = 0; p < 2; ++p) {
    int c = p * 256 + t;
    int row = c >> 3, ck = c & 7;
    size_t go = (size_t)(r0 + row) * 64 + ck * 8;
    int lo = row * 64 + ((ck ^ (row & 7)) << 3);
    *(s16x8*)&Kbf[go] = *(const s16x8*)&Xl[lo];
    *(s16x8*)&Bb[go] = *(const s16x8*)&Bl[lo];
  }
  #pragma unroll
  for (int p = 0; p < 2; ++p) {
    int c = p * 256 + t;
    int dd = c >> 3, ck = c & 7;
    *(s16x8*)&Vt[(size_t)(b * 64 + dd) * 1024 + n0 + ck * 8] =
        *(const s16x8*)&Vl[dd * 72 + ck * 8];
  }
  if (sblk && t < 64)
    scal_ws[t] = sc4[0][t] + sc4[1][t] + sc4[2][t] + sc4[3][t];
}

// P-processing: leaky (max(v,0.01v)) + optional diag-zero + pack to P^T B-frag words
#define PROC(SV, DG, PWV)                                                      \
  do {                                                                         \
    float p_[16];                                                              \
    _Pragma("unroll") for (int r_ = 0; r_ < 16; ++r_) {                        \
      float v_ = (SV)[r_];                                                     \
      p_[r_] = fmaxf(v_, 0.01f * v_);                                          \
    }                                                                          \
    if (DG) {                                                                  \
      _Pragma("unroll") for (int r_ = 0; r_ < 16; ++r_) {                      \
        int rl_ = (r_ & 3) + 8 * (r_ >> 2) + 4 * h;                            \
        p_[r_] = (rl_ == ln) ? 0.f : p_[r_];                                   \
      }                                                                        \
    }                                                                          \
    unsigned pk_[8];                                                           \
    _Pragma("unroll") for (int i_ = 0; i_ < 8; ++i_)                           \
        pk_[i_] = cvt_pk_bf16(p_[2 * i_], p_[2 * i_ + 1]);                     \
    auto a0_ = __builtin_amdgcn_permlane32_swap(pk_[0], pk_[2], false, false); \
    auto a1_ = __builtin_amdgcn_permlane32_swap(pk_[1], pk_[3], false, false); \
    auto a2_ = __builtin_amdgcn_permlane32_swap(pk_[4], pk_[6], false, false); \
    auto a3_ = __builtin_amdgcn_permlane32_swap(pk_[5], pk_[7], false, false); \
    PWV[0][0] = a0_[0]; PWV[0][1] = a1_[0]; PWV[0][2] = a0_[1];                \
    PWV[0][3] = a1_[1]; PWV[1][0] = a2_[0]; PWV[1][1] = a3_[0];                \
    PWV[1][2] = a2_[1]; PWV[1][3] = a3_[1];                                    \
  } while (0)

// ---------------- kernel 2: fused leaky(mask(Q K^T)) @ V + base ----------------
// grid (32 batch, 8 q-tile of 128). Wave = (qg: q64-group, kvh: kv-half32):
// 16 MFMA / only 8 ds_read per wave-iter (half of R10's LDS traffic).
// Ring-4 depth-3; next-iter K-frags pre-read into regs during PV (race-free:
// vmcnt(4) at iter top guarantees tile i+1 resident).
__global__ __launch_bounds__(256) void attn_kernel(
    const u16* __restrict__ Kbf, const u16* __restrict__ Vt,
    const u16* __restrict__ Bb, const float* __restrict__ scal_ws,
    float* __restrict__ Hout) {
  __shared__ __align__(16) u16 ring[4][2][4096];  // 64 KB ring-4 (K,V per slot)

  const int t = threadIdx.x;
  const int b = blockIdx.x;
  const int q0 = blockIdx.y * 128;
  const int lane = t & 63, w = t >> 6, h = lane >> 5, ln = lane & 31;
  const int qg = w & 1;    // q64 group
  const int kvh = w >> 1;  // kv half

  const u16* Kg = Kbf + (size_t)b * 65536;
  const u16* Vg = Vt + (size_t)b * 65536;

  // Q raw rows + scales (issued BEFORE stages: compiler's wait for these
  // leaves the stage-gld16s in flight)
  s16x8 qraw[2][4];
  #pragma unroll
  for (int qh = 0; qh < 2; ++qh)
    #pragma unroll
    for (int ks = 0; ks < 4; ++ks)
      qraw[qh][ks] = *(const s16x8*)(
          Kg + (size_t)(q0 + qg * 64 + qh * 32 + ln) * 64 + ks * 16 + h * 8);
  float4 sA[4], sB[4];
  #pragma unroll
  for (int ks = 0; ks < 4; ++ks) {
    sA[ks] = *(const float4*)(scal_ws + ks * 16 + h * 8);
    sB[ks] = *(const float4*)(scal_ws + ks * 16 + h * 8 + 4);
  }

  // prologue: stage tiles 0,1,2 (12 gld16/wave)
  #pragma unroll
  for (int i = 0; i < 3; ++i) {
    stage_tile64(Kg + (size_t)i * 4096, 64, &ring[i][0][0], t);
    stage_tile64(Vg + i * 64, 1024, &ring[i][1][0], t);
  }

  // qf = Q^T B-frags scaled per-feature (Q = attX * scale)
  s16x8 qf[2][4];
  #pragma unroll
  for (int qh = 0; qh < 2; ++qh)
    #pragma unroll
    for (int ks = 0; ks < 4; ++ks) {
      union { unsigned u[4]; s16x8 v; } qq;
      qq.u[0] = cvt_pk_bf16(bf2f((u16)qraw[qh][ks][0]) * sA[ks].x,
                            bf2f((u16)qraw[qh][ks][1]) * sA[ks].y);
      qq.u[1] = cvt_pk_bf16(bf2f((u16)qraw[qh][ks][2]) * sA[ks].z,
                            bf2f((u16)qraw[qh][ks][3]) * sA[ks].w);
      qq.u[2] = cvt_pk_bf16(bf2f((u16)qraw[qh][ks][4]) * sB[ks].x,
                            bf2f((u16)qraw[qh][ks][5]) * sB[ks].y);
      qq.u[3] = cvt_pk_bf16(bf2f((u16)qraw[qh][ks][6]) * sB[ks].z,
                            bf2f((u16)qraw[qh][ks][7]) * sB[ks].w);
      qf[qh][ks] = qq.v;
    }

  WAIT_VMCNT(8);  // tile 0 fully staged (tiles 1,2 in flight)
  __builtin_amdgcn_s_barrier();
  CFENCE;

  // K-frags of tile 0 into registers
  s16x8 kf[4];
  #pragma unroll
  for (int ks = 0; ks < 4; ++ks)
    kf[ks] = frag(&ring[0][0][0], kvh * 32 + ln, ks * 2 + h);

  f32x16 o00 = zero16(), o01 = zero16();  // O^T[dh0][qh0/1] partials (this kvh)
  f32x16 o10 = zero16(), o11 = zero16();  // O^T[dh1][qh0/1]

  #pragma unroll 1
  for (int i = 0; i < 16; ++i) {
    const int kv0 = i * 64;
    // tile i done was guaranteed last iter; this wait covers tile i+1 (for the
    // in-loop kf pre-read). Outstanding: (i+1):4, (i+2):4.
    if (i < 14) {
      WAIT_VMCNT(4);
    } else {
      WAIT_VMCNT(0);
    }
    __builtin_amdgcn_s_barrier();
    CFENCE;
    if (i < 13) {  // stage tile i+3 into freed slot (i-1)
      const int ns = (i + 3) & 3;
      stage_tile64(Kg + (size_t)(i + 3) * 4096, 64, &ring[ns][0][0], t);
      stage_tile64(Vg + (i + 3) * 64, 1024, &ring[ns][1][0], t);
    }
    const u16* Vl = &ring[i & 3][1][0];

    // V-frags for this wave's kv-half (issue early; consumed after PROC)
    s16x8 vf[2][2];
    #pragma unroll
    for (int dh = 0; dh < 2; ++dh)
      #pragma unroll
      for (int c = 0; c < 2; ++c)
        vf[dh][c] = frag(Vl, dh * 32 + ln, (kvh * 2 + c) * 2 + h);

    // QK: S^T[kv32][q64] — kf already in regs (pre-read last iter)
    f32x16 s0 = zero16(), s1 = zero16();
    __builtin_amdgcn_s_setprio(1);
    #pragma unroll
    for (int ks = 0; ks < 4; ++ks) {
      s0 = __builtin_amdgcn_mfma_f32_32x32x16_bf16(kf[ks], qf[0][ks], s0, 0, 0, 0);
      s1 = __builtin_amdgcn_mfma_f32_32x32x16_bf16(kf[ks], qf[1][ks], s1, 0, 0, 0);
    }
    __builtin_amdgcn_s_setprio(0);

    const bool dg0 = (kv0 + kvh * 32) == (q0 + qg * 64);
    const bool dg1 = (kv0 + kvh * 32) == (q0 + qg * 64 + 32);
    unsigned pw0[2][4], pw1[2][4];
    PROC(s0, dg0, pw0);
    PROC(s1, dg1, pw1);

    // pre-read next tile's K-frags (tile i+1 resident per this iter's vmcnt)
    if (i < 15) {
      const u16* Kn = &ring[(i + 1) & 3][0][0];
      #pragma unroll
      for (int ks = 0; ks < 4; ++ks)
        kf[ks] = frag(Kn, kvh * 32 + ln, ks * 2 + h);
    }

    // PV: O^T += V^T[:, kv-half] * P^T  (4 independent acc chains)
    __builtin_amdgcn_s_setprio(1);
    #pragma unroll
    for (int c = 0; c < 2; ++c) {
      union { unsigned u[4]; s16x8 v; } pb0, pb1;
      #pragma unroll
      for (int j = 0; j < 4; ++j) { pb0.u[j] = pw0[c][j]; pb1.u[j] = pw1[c][j]; }
      o00 = __builtin_amdgcn_mfma_f32_32x32x16_bf16(vf[0][c], pb0.v, o00, 0, 0, 0);
      o01 = __builtin_amdgcn_mfma_f32_32x32x16_bf16(vf[0][c], pb1.v, o01, 0, 0, 0);
      o10 = __builtin_amdgcn_mfma_f32_32x32x16_bf16(vf[1][c], pb0.v, o10, 0, 0, 0);
      o11 = __builtin_amdgcn_mfma_f32_32x32x16_bf16(vf[1][c], pb1.v, o11, 0, 0, 0);
    }
    __builtin_amdgcn_s_setprio(0);
  }

  __syncthreads();  // ring dead; reuse for O reduction

  // 2-round epilogue over q64-groups: kvh partials summed through LDS
  float* R0 = (float*)&ring[0][0][0];  // 16 KB [q64][d64] granule-swizzled
  float* R1 = R0 + 4096;               // 16 KB
  #pragma unroll
  for (int g = 0; g < 2; ++g) {
    if (qg == g) {
      float* Rd = kvh ? R1 : R0;
      #pragma unroll
      for (int qh = 0; qh < 2; ++qh) {
        const f32x16& oA = qh ? o01 : o00;
        const f32x16& oB = qh ? o11 : o10;
        int q = qh * 32 + ln;
        #pragma unroll
        for (int reg = 0; reg < 16; ++reg) {
          int rl = (reg & 3) + 8 * (reg >> 2) + 4 * h;
          int d0 = rl, d1 = 32 + rl;
          Rd[q * 64 + ((((d0 >> 2) ^ (q & 15)) << 2) | (d0 & 3))] = oA[reg];
          Rd[q * 64 + ((((d1 >> 2) ^ (q & 15)) << 2) | (d1 & 3))] = oB[reg];
        }
      }
    }
    __syncthreads();
    // all threads: sum partials + base, store rows q0+g*64 .. +63
    #pragma unroll
    for (int e = 0; e < 4; ++e) {
      int idx = e * 256 + t;
      int q = idx >> 4, dgp = idx & 15;
      int off = q * 64 + ((dgp ^ (q & 15)) << 2);
      float4 v0 = *(const float4*)&R0[off];
      float4 v1 = *(const float4*)&R1[off];
      size_t go = ((size_t)b * 1024 + q0 + g * 64 + q) * 64 + dgp * 4;
      const short4 bv = *(const short4*)(Bb + go);
      float4 v;
      v.x = v0.x + v1.x + bf2f((u16)bv.x);
      v.y = v0.y + v1.y + bf2f((u16)bv.y);
      v.z = v0.z + v1.z + bf2f((u16)bv.z);
      v.w = v0.w + v1.w + bf2f((u16)bv.w);
      *(float4*)(Hout + go) = v;
    }
    if (g == 0) __syncthreads();  // before round 1 overwrites R0/R1
  }
}

extern "C" void kernel_launch(void* const* d_in, const int* in_sizes, int n_in,
                              void* d_out, int out_size, void* d_ws, size_t ws_size,
                              hipStream_t stream) {
  const float* X = (const float*)d_in[0];
  // d_in[1] = A : unused by the forward pass
  const float* W = (const float*)d_in[2];
  const float* attW = (const float*)d_in[3];
  const float* a = (const float*)d_in[4];
  const float* biasW = (const float*)d_in[5];
  const float* selfW = (const float*)d_in[6];
  float* H = (float*)d_out;

  u16* Kbf = (u16*)d_ws;                                // 4 MB
  u16* Vt = Kbf + (size_t)32 * 1024 * 64;               // 4 MB
  u16* Bb = Vt + (size_t)32 * 1024 * 64;                // 4 MB
  float* scal = (float*)(Bb + (size_t)32 * 1024 * 64);  // 256 B

  prep_kernel<<<dim3(32, 16), 256, 0, stream>>>(X, W, attW, a, biasW, selfW,
                                                Kbf, Vt, Bb, scal);
  attn_kernel<<<dim3(32, 8), 256, 0, stream>>>(Kbf, Vt, Bb, scal, H);
}